// Round 1
// baseline (313.190 us; speedup 1.0000x reference)
//
#include <hip/hip_runtime.h>
#include <hip/hip_bf16.h>

typedef __attribute__((ext_vector_type(8))) _Float16 f16x8;
typedef __attribute__((ext_vector_type(4))) _Float16 f16x4;
typedef __attribute__((ext_vector_type(4))) float f32x4;

// ---------------------------------------------------------------- cast f32 -> f16
__global__ __launch_bounds__(256) void cast_f32_f16(const float* __restrict__ s,
                                                    _Float16* __restrict__ d, int n) {
  int i = (blockIdx.x * blockDim.x + threadIdx.x) * 4;
  if (i >= n) return;
  float4 v = *reinterpret_cast<const float4*>(s + i);
  f16x4 h = {(_Float16)v.x, (_Float16)v.y, (_Float16)v.z, (_Float16)v.w};
  *reinterpret_cast<f16x4*>(d + i) = h;
}

// ---------------------------------------------------------------- GEMM C = A @ B^T + bias
// A [M,K] f16 row-major, Bm [N,K] f16 row-major. 128x128 tile, BK=32, 4 waves (2x2 of 64x64).
// EPI=0: scatter to Q [bh][L][64], K [bh][L][64], Vt [bh][64][L] (all f16)
// EPI=1: Cout[M,N] fp32
template <int EPI>
__global__ __launch_bounds__(256) void gemm_bt(
    const _Float16* __restrict__ A, const _Float16* __restrict__ Bm,
    const float* __restrict__ bias, float* __restrict__ Cout,
    _Float16* __restrict__ Qo, _Float16* __restrict__ Ko, _Float16* __restrict__ Vto,
    int Ndim, int Kdim) {
  __shared__ __align__(16) _Float16 As[128][40];  // pad 32->40: 80B rows, 2-way bank alias only
  __shared__ __align__(16) _Float16 Bs[128][40];
  const int tid = threadIdx.x;
  const int lane = tid & 63;
  const int wave = tid >> 6;
  const int wm = wave >> 1, wn = wave & 1;
  const int m0 = blockIdx.y * 128, n0 = blockIdx.x * 128;
  const int r = tid >> 2;           // staging row 0..63
  const int kc = (tid & 3) * 8;     // staging k-offset (halves)
  const int row = lane & 15;        // fragment row/col within 16
  const int kk = (lane >> 4) * 8;   // fragment k-offset

  f32x4 acc[4][4];
#pragma unroll
  for (int i = 0; i < 4; ++i)
#pragma unroll
    for (int j = 0; j < 4; ++j)
#pragma unroll
      for (int q = 0; q < 4; ++q) acc[i][j][q] = 0.f;

  for (int k0 = 0; k0 < Kdim; k0 += 32) {
    *reinterpret_cast<uint4*>(&As[r][kc]) =
        *reinterpret_cast<const uint4*>(&A[(size_t)(m0 + r) * Kdim + k0 + kc]);
    *reinterpret_cast<uint4*>(&As[r + 64][kc]) =
        *reinterpret_cast<const uint4*>(&A[(size_t)(m0 + r + 64) * Kdim + k0 + kc]);
    *reinterpret_cast<uint4*>(&Bs[r][kc]) =
        *reinterpret_cast<const uint4*>(&Bm[(size_t)(n0 + r) * Kdim + k0 + kc]);
    *reinterpret_cast<uint4*>(&Bs[r + 64][kc]) =
        *reinterpret_cast<const uint4*>(&Bm[(size_t)(n0 + r + 64) * Kdim + k0 + kc]);
    __syncthreads();
    f16x8 af[4], bf[4];
#pragma unroll
    for (int i = 0; i < 4; ++i)
      af[i] = *reinterpret_cast<const f16x8*>(&As[wm * 64 + i * 16 + row][kk]);
#pragma unroll
    for (int j = 0; j < 4; ++j)
      bf[j] = *reinterpret_cast<const f16x8*>(&Bs[wn * 64 + j * 16 + row][kk]);
#pragma unroll
    for (int i = 0; i < 4; ++i)
#pragma unroll
      for (int j = 0; j < 4; ++j)
        acc[i][j] = __builtin_amdgcn_mfma_f32_16x16x32_f16(af[i], bf[j], acc[i][j], 0, 0, 0);
    __syncthreads();
  }

  // C/D layout: col = lane&15, row = (lane>>4)*4 + reg  (verified m89/m91)
#pragma unroll
  for (int i = 0; i < 4; ++i) {
#pragma unroll
    for (int j = 0; j < 4; ++j) {
#pragma unroll
      for (int q = 0; q < 4; ++q) {
        const int gm = m0 + wm * 64 + i * 16 + (lane >> 4) * 4 + q;
        const int gn = n0 + wn * 64 + j * 16 + row;
        const float c = acc[i][j][q] + bias[gn];
        if (EPI == 1) {
          Cout[(size_t)gm * Ndim + gn] = c;
        } else {
          const int b = gm >> 11, l = gm & 2047;
          const int part = gn >> 10, dD = gn & 1023;
          const int h = dD >> 6, dd = dD & 63;
          const int bh = b * 16 + h;
          const _Float16 ch = (_Float16)c;
          if (part == 0)
            Qo[((size_t)bh * 2048 + l) * 64 + dd] = ch;
          else if (part == 1)
            Ko[((size_t)bh * 2048 + l) * 64 + dd] = ch;
          else
            Vto[((size_t)bh * 64 + dd) * 2048 + l] = ch;
        }
      }
    }
  }
}

// ---------------------------------------------------------------- flash attention
// grid: 32 bh * 32 qtiles. Block = 4 waves; each wave owns 16 q-rows, iterates KV in tiles of 32.
__global__ __launch_bounds__(256) void attn_fwd(const _Float16* __restrict__ Qh,
                                                const _Float16* __restrict__ Kh,
                                                const _Float16* __restrict__ Vth,
                                                _Float16* __restrict__ AOh) {
  __shared__ __align__(16) _Float16 Plds[4][16][40];
  const int tid = threadIdx.x, lane = tid & 63, wave = tid >> 6;
  const int bh = blockIdx.x >> 5;
  const int q0 = (blockIdx.x & 31) * 64 + wave * 16;
  const int b = bh >> 4, h = bh & 15;
  const _Float16* Qp = Qh + ((size_t)bh * 2048 + q0) * 64;
  const _Float16* Kp = Kh + (size_t)bh * 2048 * 64;
  const _Float16* Vp = Vth + (size_t)bh * 64 * 2048;
  const int row = lane & 15, kk = (lane >> 4) * 8;

  const f16x8 qf0 = *reinterpret_cast<const f16x8*>(&Qp[row * 64 + kk]);
  const f16x8 qf1 = *reinterpret_cast<const f16x8*>(&Qp[row * 64 + 32 + kk]);

  f32x4 o[4];
  float mrun[4], lrun[4];
#pragma unroll
  for (int n = 0; n < 4; ++n)
#pragma unroll
    for (int q = 0; q < 4; ++q) o[n][q] = 0.f;
#pragma unroll
  for (int q = 0; q < 4; ++q) { mrun[q] = -1e30f; lrun[q] = 0.f; }

  for (int kv = 0; kv < 2048; kv += 32) {
    f32x4 s0, s1;
#pragma unroll
    for (int q = 0; q < 4; ++q) { s0[q] = 0.f; s1[q] = 0.f; }
    {
      const f16x8 k0a = *reinterpret_cast<const f16x8*>(&Kp[(size_t)(kv + row) * 64 + kk]);
      const f16x8 k0b = *reinterpret_cast<const f16x8*>(&Kp[(size_t)(kv + row) * 64 + 32 + kk]);
      s0 = __builtin_amdgcn_mfma_f32_16x16x32_f16(qf0, k0a, s0, 0, 0, 0);
      s0 = __builtin_amdgcn_mfma_f32_16x16x32_f16(qf1, k0b, s0, 0, 0, 0);
      const f16x8 k1a = *reinterpret_cast<const f16x8*>(&Kp[(size_t)(kv + 16 + row) * 64 + kk]);
      const f16x8 k1b = *reinterpret_cast<const f16x8*>(&Kp[(size_t)(kv + 16 + row) * 64 + 32 + kk]);
      s1 = __builtin_amdgcn_mfma_f32_16x16x32_f16(qf0, k1a, s1, 0, 0, 0);
      s1 = __builtin_amdgcn_mfma_f32_16x16x32_f16(qf1, k1b, s1, 0, 0, 0);
    }
    float mt[4];
#pragma unroll
    for (int q = 0; q < 4; ++q) {
      s0[q] *= 0.125f;
      s1[q] *= 0.125f;
      mt[q] = fmaxf(s0[q], s1[q]);
    }
#pragma unroll
    for (int d = 1; d < 16; d <<= 1)
#pragma unroll
      for (int q = 0; q < 4; ++q) mt[q] = fmaxf(mt[q], __shfl_xor(mt[q], d));
    float alpha[4], p0[4], p1[4], rs[4];
#pragma unroll
    for (int q = 0; q < 4; ++q) {
      const float mn = fmaxf(mrun[q], mt[q]);
      alpha[q] = __expf(mrun[q] - mn);
      mrun[q] = mn;
      p0[q] = __expf(s0[q] - mn);
      p1[q] = __expf(s1[q] - mn);
      rs[q] = p0[q] + p1[q];
    }
#pragma unroll
    for (int d = 1; d < 16; d <<= 1)
#pragma unroll
      for (int q = 0; q < 4; ++q) rs[q] += __shfl_xor(rs[q], d);
#pragma unroll
    for (int q = 0; q < 4; ++q) lrun[q] = lrun[q] * alpha[q] + rs[q];
#pragma unroll
    for (int n = 0; n < 4; ++n)
#pragma unroll
      for (int q = 0; q < 4; ++q) o[n][q] *= alpha[q];
    // P (16q x 32k) -> per-wave LDS for PV A-fragment re-layout
#pragma unroll
    for (int q = 0; q < 4; ++q) {
      Plds[wave][(lane >> 4) * 4 + q][row] = (_Float16)p0[q];
      Plds[wave][(lane >> 4) * 4 + q][16 + row] = (_Float16)p1[q];
    }
    __syncthreads();
    const f16x8 pf = *reinterpret_cast<const f16x8*>(&Plds[wave][row][kk]);
#pragma unroll
    for (int n = 0; n < 4; ++n) {
      const f16x8 vf =
          *reinterpret_cast<const f16x8*>(&Vp[(size_t)(n * 16 + row) * 2048 + kv + kk]);
      o[n] = __builtin_amdgcn_mfma_f32_16x16x32_f16(pf, vf, o[n], 0, 0, 0);
    }
    __syncthreads();
  }
  float inv[4];
#pragma unroll
  for (int q = 0; q < 4; ++q) inv[q] = 1.f / lrun[q];
#pragma unroll
  for (int n = 0; n < 4; ++n)
#pragma unroll
    for (int q = 0; q < 4; ++q) {
      const size_t grow = (size_t)b * 2048 + q0 + (lane >> 4) * 4 + q;
      const int gcol = h * 64 + n * 16 + row;
      AOh[grow * 1024 + gcol] = (_Float16)(o[n][q] * inv[q]);
    }
}

// ---------------------------------------------------------------- launcher
extern "C" void kernel_launch(void* const* d_in, const int* in_sizes, int n_in, void* d_out,
                              int out_size, void* d_ws, size_t ws_size, hipStream_t stream) {
  const float* x = (const float*)d_in[0];
  const float* Wqkv = (const float*)d_in[1];
  const float* bqkv = (const float*)d_in[2];
  const float* Wout = (const float*)d_in[3];
  const float* bout = (const float*)d_in[4];
  float* out = (float*)d_out;

  char* ws = (char*)d_ws;
  _Float16* xh = (_Float16*)(ws);                  // 4096*1024       (8 MB)
  _Float16* wqkvh = (_Float16*)(ws + 8388608);     // 3072*1024       (6 MB)
  _Float16* wouth = (_Float16*)(ws + 14680064);    // 1024*1024       (2 MB)
  _Float16* Qh = (_Float16*)(ws + 16777216);       // [32][2048][64]  (8 MB)
  _Float16* Kh = (_Float16*)(ws + 25165824);       // [32][2048][64]  (8 MB)
  _Float16* Vth = (_Float16*)(ws + 33554432);      // [32][64][2048]  (8 MB)
  _Float16* AOh = (_Float16*)(ws + 41943040);      // 4096*1024       (8 MB)

  cast_f32_f16<<<4096, 256, 0, stream>>>(x, xh, 4194304);
  cast_f32_f16<<<3072, 256, 0, stream>>>(Wqkv, wqkvh, 3145728);
  cast_f32_f16<<<1024, 256, 0, stream>>>(Wout, wouth, 1048576);

  gemm_bt<0><<<dim3(24, 32), 256, 0, stream>>>(xh, wqkvh, bqkv, nullptr, Qh, Kh, Vth, 3072, 1024);
  attn_fwd<<<1024, 256, 0, stream>>>(Qh, Kh, Vth, AOh);
  gemm_bt<1><<<dim3(8, 32), 256, 0, stream>>>(AOh, wouth, bout, out, nullptr, nullptr, nullptr,
                                              1024, 1024);
}